// Round 11
// baseline (324.053 us; speedup 1.0000x reference)
//
#include <hip/hip_runtime.h>
#include <hip/hip_bf16.h>

// GCN: h = (0.5A)^2 x ; h = relu(h W1 + b1) ; h = (0.5A)^2 h ; h = h W2 + b2
// Rewrites:
//  - (0.5A)^2 (relu(...)) W2 + b2 == (0.5A)^2 (relu(...) W2) + b2
//  - SpMMs via on-device CSR, gather-side, zero float atomics
//  - intermediates bf16 (RTN), fp32 accumulation (r9)
//  - dense layer on MFMA 16x16x32 bf16 (r10)
//  - r11 (this):
//    * cv packed 4B/edge: col 17b | val 15b (positive bf16, no sign bit).
//      Halves cv traffic per pass; uint4 load = 4 edges.
//    * spmm software pipeline: align-to-4 head, 4-wide batches with
//      one-batch cv lookahead (breaks cv->gather dependency chain).
//    * launches 11 -> 9: convert folded into K1; K2a/K2b merged (bases
//      written to partial2 to avoid in-place race).
// Buffers (d_out used as raw scratch until final write):
//  xb  = d_out[0,6.4MB)      bf16 x          t0b = d_out[6.4,12.8MB)
//  t2b = d_out[12.8,25.6MB)  t1b = t3b = ws[0,12.8MB) (stg overlays, dead by s2)
//  s5: out = spmm64(t3b) + b2 -> d_out fp32 (overwrites scratch)

#define REGION_SHIFT 9               // 512 rows per region
#define REGION_SIZE  (1 << REGION_SHIFT)
#define COL_MASK 0x1FFFF             // 17 bits, N=100000 < 131072
#define GBUILD 256                   // blocks for K1/K3 (chunking must match!)

typedef unsigned short u16;
typedef unsigned int   u32;
typedef __attribute__((ext_vector_type(8))) short bf16x8;
typedef __attribute__((ext_vector_type(4))) float f32x4;

__device__ inline float bflo(u32 w) { return __uint_as_float(w << 16); }
__device__ inline float bfhi(u32 w) { return __uint_as_float(w & 0xffff0000u); }
// pack two fp32 -> bf16 pair (RTN-even), a in low half
__device__ inline u32 bfpack(float a, float b) {
    u32 ua = __float_as_uint(a), ub = __float_as_uint(b);
    ua = (ua + 0x7fffu + ((ua >> 16) & 1u)) >> 16;
    ub = (ub + 0x7fffu + ((ub >> 16) & 1u)) & 0xffff0000u;
    return ua | ub;
}
__device__ inline u16 bf1(float f) {
    u32 u = __float_as_uint(f);
    return (u16)((u + 0x7fffu + ((u >> 16) & 1u)) >> 16);
}

// ---- K1: fp32->bf16 convert (grid-stride) + per-block LDS region hist ----
__global__ void region_count_kernel(const int* __restrict__ er, int E,
                                    int* __restrict__ partial,
                                    const float* __restrict__ x,
                                    u16* __restrict__ xb, int n4) {
    // convert x -> xb (independent work, folded to save a launch)
    for (int i = blockIdx.x * 256 + threadIdx.x; i < n4; i += gridDim.x * 256) {
        float4 a = reinterpret_cast<const float4*>(x)[i];
        uint2 o;
        o.x = bfpack(a.x, a.y);
        o.y = bfpack(a.z, a.w);
        reinterpret_cast<uint2*>(xb)[i] = o;
    }
    __shared__ int hist[256];
    int t = threadIdx.x;
    hist[t] = 0;
    __syncthreads();
    int chunk = (E + gridDim.x - 1) / gridDim.x;
    int s = blockIdx.x * chunk;
    int e = min(E, s + chunk);
    for (int i = s + t; i < e; i += 256)
        atomicAdd(&hist[er[i] >> REGION_SHIFT], 1);
    __syncthreads();
    partial[blockIdx.x * 256 + t] = hist[t];   // single-writer 1KB row
}

// ---- K2: merged scan. Every block redundantly computes region totals+scan
// in LDS; block 0 writes region_off; block r writes per-(block,region r)
// scatter bases into partial2 (separate array: no read/write race).
__global__ void region_scan2_kernel(const int* __restrict__ partial,
                                    int* __restrict__ partial2,
                                    int* __restrict__ region_off,
                                    int nreg, int E, int G) {
    __shared__ int tot[256], sc[256];
    int cb = blockIdx.x;
    int t = threadIdx.x;
    int total = 0;
    for (int b = 0; b < G; b++) total += partial[b * 256 + t];  // coalesced
    tot[t] = (t < nreg) ? total : 0;
    __syncthreads();
    sc[t] = tot[t];
    __syncthreads();
    for (int off = 1; off < 256; off <<= 1) {
        int x = (t >= off) ? sc[t - off] : 0;
        __syncthreads();
        sc[t] += x;
        __syncthreads();
    }
    if (cb == 0) {
        if (t < nreg) region_off[t] = sc[t] - tot[t];
        if (t == 0) region_off[nreg] = E;
    }
    if (cb >= nreg) return;
    int base_cb = sc[cb] - tot[cb];      // region cb start
    int c = partial[t * 256 + cb];       // block t's count for region cb
    __syncthreads();
    sc[t] = c;
    __syncthreads();
    for (int off = 1; off < 256; off <<= 1) {
        int x = (t >= off) ? sc[t - off] : 0;
        __syncthreads();
        sc[t] += x;
        __syncthreads();
    }
    partial2[t * 256 + cb] = base_cb + sc[t] - c;   // exclusive base
}

// ---- K3: coarse scatter, LDS rank only (no global atomics) ----
// stg rec: .x = col | localrow<<17 ; .y = bf16 bits of 0.5*val (15 bits, >=0)
__global__ void coarse_scatter_kernel(const int* __restrict__ er,
                                      const int* __restrict__ ec,
                                      const float* __restrict__ ev, int E,
                                      const int* __restrict__ partial2,
                                      int2* __restrict__ stg) {
    __shared__ int cnt2[256], gbase[256];
    int t = threadIdx.x;
    cnt2[t] = 0;
    gbase[t] = partial2[blockIdx.x * 256 + t];
    __syncthreads();
    int chunk = (E + gridDim.x - 1) / gridDim.x;   // identical to K1
    int s0 = blockIdx.x * chunk;
    int e0 = min(E, s0 + chunk);
    for (int i = s0 + t; i < e0; i += 256) {
        int r = er[i];
        int b = r >> REGION_SHIFT;
        int rank = atomicAdd(&cnt2[b], 1);
        int2 rec;
        rec.x = ec[i] | ((r & (REGION_SIZE - 1)) << 17);
        rec.y = (int)bf1(0.5f * ev[i]);            // positive: 15 bits
        stg[gbase[b] + rank] = rec;                // block-private run
    }
}

// ---- K4: per-region LDS sort -> row_ptr + packed 4B cv ----
__global__ void region_sort_kernel(const int2* __restrict__ stg,
                                   const int* __restrict__ region_off,
                                   int* __restrict__ row_ptr,
                                   u32* __restrict__ cv, int N, int E) {
    __shared__ int hist[REGION_SIZE];
    __shared__ int wp_local[REGION_SIZE];
    __shared__ int psum[256];
    int cb = blockIdx.x;
    int lo = cb << REGION_SHIFT;
    if (lo >= N) return;
    int hi = min(lo + REGION_SIZE, N);
    int cnt = hi - lo;
    int t = threadIdx.x;
    for (int r = t; r < cnt; r += 256) hist[r] = 0;
    __syncthreads();
    int start = region_off[cb];
    int end   = region_off[cb + 1];
    for (int q = start + t; q < end; q += 256)
        atomicAdd(&hist[stg[q].x >> 17], 1);
    __syncthreads();
    int a0 = (2 * t     < cnt) ? hist[2 * t]     : 0;
    int a1 = (2 * t + 1 < cnt) ? hist[2 * t + 1] : 0;
    psum[t] = a0 + a1;
    __syncthreads();
    for (int off = 1; off < 256; off <<= 1) {
        int x = (t >= off) ? psum[t - off] : 0;
        __syncthreads();
        psum[t] += x;
        __syncthreads();
    }
    int excl = psum[t] - (a0 + a1);
    if (2 * t < cnt) {
        wp_local[2 * t] = start + excl;
        row_ptr[lo + 2 * t] = start + excl;
    }
    if (2 * t + 1 < cnt) {
        wp_local[2 * t + 1] = start + excl + a0;
        row_ptr[lo + 2 * t + 1] = start + excl + a0;
    }
    if (cb == 0 && t == 0) row_ptr[N] = E;
    __syncthreads();
    for (int q = start + t; q < end; q += 256) {
        int2 e = stg[q];
        int lr = e.x >> 17;
        int p = atomicAdd(&wp_local[lr], 1);      // LDS atomic
        cv[p] = ((u32)e.y << 17) | ((u32)e.x & COL_MASK);  // private window
    }
}

// ---------------- CSR SpMM, gather-side, bf16 table / fp32 accum ------------
__device__ inline void fma8(float acc[8], float v, uint4 w) {
    acc[0] = fmaf(v, bflo(w.x), acc[0]); acc[1] = fmaf(v, bfhi(w.x), acc[1]);
    acc[2] = fmaf(v, bflo(w.y), acc[2]); acc[3] = fmaf(v, bfhi(w.y), acc[3]);
    acc[4] = fmaf(v, bflo(w.z), acc[4]); acc[5] = fmaf(v, bfhi(w.z), acc[5]);
    acc[6] = fmaf(v, bflo(w.w), acc[6]); acc[7] = fmaf(v, bfhi(w.w), acc[7]);
}
__device__ inline float cvval(u32 q) { return __uint_as_float((q >> 17) << 16); }

// D features/row; 8 features (16B) per lane; LPR = D/8 lanes per row.
template <int D, bool FINAL>
__global__ __launch_bounds__(256) void spmm_bf16_kernel(
        const u16* __restrict__ h,
        const int* __restrict__ row_ptr,
        const u32* __restrict__ cv,
        void* __restrict__ outp,
        const float* __restrict__ bias,  // used iff FINAL
        int N) {
    constexpr int LPR = D / 8;
    int gid = blockIdx.x * 256 + threadIdx.x;
    int row = gid / LPR;
    int sub = gid % LPR;
    if (row >= N) return;
    int start = row_ptr[row];
    int end   = row_ptr[row + 1];
    float acc[8] = {0.f, 0.f, 0.f, 0.f, 0.f, 0.f, 0.f, 0.f};
    int j = start;
    // head: align j to 4-edge boundary (cv base is 16B aligned)
    while (j < end && (j & 3)) {
        u32 q = cv[j++];
        uint4 w = reinterpret_cast<const uint4*>(h + (size_t)(q & COL_MASK) * D)[sub];
        fma8(acc, cvval(q), w);
    }
    int nv = (end - j) >> 2;
    if (nv > 0) {
        const uint4* cv4 = reinterpret_cast<const uint4*>(cv + j);
        uint4 q = cv4[0];
        for (int it = 1; it <= nv; it++) {
            uint4 qn = (it < nv) ? cv4[it] : q;   // one-batch lookahead
            uint4 w0 = reinterpret_cast<const uint4*>(h + (size_t)(q.x & COL_MASK) * D)[sub];
            uint4 w1 = reinterpret_cast<const uint4*>(h + (size_t)(q.y & COL_MASK) * D)[sub];
            uint4 w2 = reinterpret_cast<const uint4*>(h + (size_t)(q.z & COL_MASK) * D)[sub];
            uint4 w3 = reinterpret_cast<const uint4*>(h + (size_t)(q.w & COL_MASK) * D)[sub];
            fma8(acc, cvval(q.x), w0);
            fma8(acc, cvval(q.y), w1);
            fma8(acc, cvval(q.z), w2);
            fma8(acc, cvval(q.w), w3);
            q = qn;
        }
        j += nv << 2;
    }
    for (; j < end; j++) {
        u32 q = cv[j];
        uint4 w = reinterpret_cast<const uint4*>(h + (size_t)(q & COL_MASK) * D)[sub];
        fma8(acc, cvval(q), w);
    }
    if (FINAL) {
        float* op = (float*)outp + (size_t)row * 64 + sub * 8;
#pragma unroll
        for (int k = 0; k < 8; k++) acc[k] += bias[sub * 8 + k];
        reinterpret_cast<float4*>(op)[0] = make_float4(acc[0], acc[1], acc[2], acc[3]);
        reinterpret_cast<float4*>(op)[1] = make_float4(acc[4], acc[5], acc[6], acc[7]);
    } else {
        u16* ob = (u16*)outp + (size_t)row * D + sub * 8;
        uint4 o;
        o.x = bfpack(acc[0], acc[1]);
        o.y = bfpack(acc[2], acc[3]);
        o.z = bfpack(acc[4], acc[5]);
        o.w = bfpack(acc[6], acc[7]);
        reinterpret_cast<uint4*>(ob)[0] = o;
    }
}

// ------- MFMA dense: t2 = relu(t1@W1 + b1) @ W2, bf16 in/out ----------------
// One wave per 16-row tile. 16x16x32 bf16 MFMA. (verified r10)
__global__ __launch_bounds__(256) void dense_mfma_kernel(
        const u16* __restrict__ h,     // [N,32] bf16
        const float* __restrict__ W1,  // [32,64]
        const float* __restrict__ b1,  // [64]
        const float* __restrict__ W2,  // [64,64]
        u16* __restrict__ outb, int N) {
    __shared__ __align__(16) u16 tiles[4][16][80];  // per-wave tile, pad 80
    int tid = threadIdx.x;
    int lane = tid & 63;
    int wave = tid >> 6;
    int n16 = lane & 15;
    int quad = lane >> 4;
    u16 (*tile)[80] = tiles[wave];

    int tilebase = (blockIdx.x * 4 + wave) * 16;
    if (tilebase >= N) return;          // wave-uniform

    bf16x8 w1f[4];
    bf16x8 w2f[4][2];
#pragma unroll
    for (int t = 0; t < 4; t++) {
#pragma unroll
        for (int j = 0; j < 8; j++) {
            int k = quad * 8 + j;
            w1f[t][j] = (short)bf1(W1[k * 64 + t * 16 + n16]);
            w2f[t][0][j] = (short)bf1(W2[k * 64 + t * 16 + n16]);
            w2f[t][1][j] = (short)bf1(W2[(32 + k) * 64 + t * 16 + n16]);
        }
    }
    float b1v[4];
#pragma unroll
    for (int t = 0; t < 4; t++) b1v[t] = b1[t * 16 + n16];

    int arow = min(tilebase + n16, N - 1);
    bf16x8 a1 = *reinterpret_cast<const bf16x8*>(h + (size_t)arow * 32 + quad * 8);
    f32x4 zero = {0.f, 0.f, 0.f, 0.f};
    f32x4 c[4];
#pragma unroll
    for (int t = 0; t < 4; t++)
        c[t] = __builtin_amdgcn_mfma_f32_16x16x32_bf16(a1, w1f[t], zero, 0, 0, 0);

#pragma unroll
    for (int t = 0; t < 4; t++)
#pragma unroll
        for (int i = 0; i < 4; i++)
            tile[quad * 4 + i][t * 16 + n16] = bf1(fmaxf(c[t][i] + b1v[t], 0.f));

    bf16x8 a2_0 = *reinterpret_cast<const bf16x8*>(&tile[n16][quad * 8]);
    bf16x8 a2_1 = *reinterpret_cast<const bf16x8*>(&tile[n16][32 + quad * 8]);
    f32x4 d[4];
#pragma unroll
    for (int t = 0; t < 4; t++) {
        d[t] = __builtin_amdgcn_mfma_f32_16x16x32_bf16(a2_0, w2f[t][0], zero, 0, 0, 0);
        d[t] = __builtin_amdgcn_mfma_f32_16x16x32_bf16(a2_1, w2f[t][1], d[t], 0, 0, 0);
    }

#pragma unroll
    for (int t = 0; t < 4; t++)
#pragma unroll
        for (int i = 0; i < 4; i++)
            tile[quad * 4 + i][t * 16 + n16] = bf1(d[t][i]);

#pragma unroll
    for (int half = 0; half < 2; half++) {
        int g = half * 512 + lane * 8;
        int r = g >> 6, cc = g & 63;
        int grow = tilebase + r;
        if (grow < N)
            *reinterpret_cast<uint4*>(outb + (size_t)grow * 64 + cc) =
                *reinterpret_cast<const uint4*>(&tile[r][cc]);
    }
}

extern "C" void kernel_launch(void* const* d_in, const int* in_sizes, int n_in,
                              void* d_out, int out_size, void* d_ws, size_t ws_size,
                              hipStream_t stream) {
    const float* x        = (const float*)d_in[0];
    const float* edge_val = (const float*)d_in[1];
    const int*   edge_row = (const int*)d_in[2];
    const int*   edge_col = (const int*)d_in[3];
    const float* W1       = (const float*)d_in[4];
    const float* b1       = (const float*)d_in[5];
    const float* W2       = (const float*)d_in[6];
    const float* b2       = (const float*)d_in[7];
    float* out = (float*)d_out;

    const int N = in_sizes[0] / 32;   // 100000
    const int E = in_sizes[1];        // 1600000
    const int NREG = (N + REGION_SIZE - 1) >> REGION_SHIFT;  // 196

    // --- d_out as raw scratch (fp32 final write overwrites all) ---
    u16* xb  = (u16*)d_out;                    // N*32 bf16
    u16* t0b = xb + (size_t)N * 32;            // N*32 bf16
    u16* t2b = (u16*)d_out + (size_t)N * 64;   // N*64 bf16 (bytes [12.8,25.6MB))

    // --- ws layout ---
    u16*  wsb = (u16*)d_ws;                    // N*64 bf16: t1b then t3b
    int2* stg = (int2*)d_ws;                   // E int2 overlay (build only)
    int*  row_ptr    = (int*)((char*)d_ws + (size_t)N * 64 * 2);  // N+1
    int*  region_off = row_ptr + (N + 1);      // NREG+1
    int*  partial    = region_off + (NREG + 1);// GBUILD*256
    int*  partial2   = partial + GBUILD * 256; // GBUILD*256
    size_t cvOff = (size_t)((char*)(partial2 + GBUILD * 256) - (char*)d_ws);
    cvOff = (cvOff + 15) & ~(size_t)15;        // 16B align for uint4 loads
    u32* cv = (u32*)((char*)d_ws + cvOff);     // E packed 4B edges
    u16* t1b = wsb;
    u16* t3b = wsb;

    int n4 = (N * 32) / 4;

    // ---- CSR build (2-pass radix, zero global atomics, no memset) ----
    region_count_kernel<<<GBUILD, 256, 0, stream>>>(edge_row, E, partial, x, xb, n4);
    region_scan2_kernel<<<NREG, 256, 0, stream>>>(partial, partial2, region_off,
                                                  NREG, E, GBUILD);
    coarse_scatter_kernel<<<GBUILD, 256, 0, stream>>>(edge_row, edge_col, edge_val,
                                                      E, partial2, stg);
    region_sort_kernel<<<NREG, 256, 0, stream>>>(stg, region_off, row_ptr, cv, N, E);

    // ---- pipeline ----
    int g32 = (N * 4 + 255) / 256;   // D=32: 4 lanes/row
    int g64 = (N * 8 + 255) / 256;   // D=64: 8 lanes/row

    spmm_bf16_kernel<32, false><<<g32, 256, 0, stream>>>(xb, row_ptr, cv, t0b, nullptr, N);
    spmm_bf16_kernel<32, false><<<g32, 256, 0, stream>>>(t0b, row_ptr, cv, t1b, nullptr, N);
    dense_mfma_kernel<<<(N + 63) / 64, 256, 0, stream>>>(t1b, W1, b1, W2, t2b, N);
    spmm_bf16_kernel<64, false><<<g64, 256, 0, stream>>>(t2b, row_ptr, cv, t3b, nullptr, N);
    spmm_bf16_kernel<64, true><<<g64, 256, 0, stream>>>(t3b, row_ptr, cv, out, b2, N);
}

// Round 12
// 300.885 us; speedup vs baseline: 1.0770x; 1.0770x over previous
//
#include <hip/hip_runtime.h>
#include <hip/hip_bf16.h>

// GCN: h = (0.5A)^2 x ; h = relu(h W1 + b1) ; h = (0.5A)^2 h ; h = h W2 + b2
// Rewrites:
//  - (0.5A)^2 (relu(...)) W2 + b2 == (0.5A)^2 (relu(...) W2) + b2
//  - SpMMs via on-device CSR, gather-side, zero float atomics
//  - intermediates bf16 (RTN), fp32 accumulation (r9)
//  - dense layer on MFMA 16x16x32 bf16 (r10)
//  - cv packed 4B/edge: col 17b | val 15b (positive bf16, no sign) (r11)
//  - r12: unbundle r11's regression. KEEP 4B cv + convert-in-K1.
//    REVERT spmm loop to r10's simple 4-wide unroll (r11's head-align loop
//    + lookahead select regressed 307->324: divergence + defeated compiler
//    scheduling). REVERT merged K2 (196 redundant 256KB sweeps) to K2a/K2b.
// Buffers (d_out used as raw scratch until final write):
//  xb  = d_out[0,6.4MB)      bf16 x          t0b = d_out[6.4,12.8MB)
//  t2b = d_out[12.8,25.6MB)  t1b = t3b = ws[0,12.8MB) (stg overlays, dead by s2)
//  s5: out = spmm64(t3b) + b2 -> d_out fp32 (overwrites scratch)

#define REGION_SHIFT 9               // 512 rows per region
#define REGION_SIZE  (1 << REGION_SHIFT)
#define COL_MASK 0x1FFFF             // 17 bits, N=100000 < 131072
#define GBUILD 256                   // blocks for K1/K3 (chunking must match!)

typedef unsigned short u16;
typedef unsigned int   u32;
typedef __attribute__((ext_vector_type(8))) short bf16x8;
typedef __attribute__((ext_vector_type(4))) float f32x4;

__device__ inline float bflo(u32 w) { return __uint_as_float(w << 16); }
__device__ inline float bfhi(u32 w) { return __uint_as_float(w & 0xffff0000u); }
// pack two fp32 -> bf16 pair (RTN-even), a in low half
__device__ inline u32 bfpack(float a, float b) {
    u32 ua = __float_as_uint(a), ub = __float_as_uint(b);
    ua = (ua + 0x7fffu + ((ua >> 16) & 1u)) >> 16;
    ub = (ub + 0x7fffu + ((ub >> 16) & 1u)) & 0xffff0000u;
    return ua | ub;
}
__device__ inline u16 bf1(float f) {
    u32 u = __float_as_uint(f);
    return (u16)((u + 0x7fffu + ((u >> 16) & 1u)) >> 16);
}

// ---- K1: fp32->bf16 convert (grid-stride) + per-block LDS region hist ----
__global__ void region_count_kernel(const int* __restrict__ er, int E,
                                    int* __restrict__ partial,
                                    const float* __restrict__ x,
                                    u16* __restrict__ xb, int n4) {
    for (int i = blockIdx.x * 256 + threadIdx.x; i < n4; i += gridDim.x * 256) {
        float4 a = reinterpret_cast<const float4*>(x)[i];
        uint2 o;
        o.x = bfpack(a.x, a.y);
        o.y = bfpack(a.z, a.w);
        reinterpret_cast<uint2*>(xb)[i] = o;
    }
    __shared__ int hist[256];
    int t = threadIdx.x;
    hist[t] = 0;
    __syncthreads();
    int chunk = (E + gridDim.x - 1) / gridDim.x;
    int s = blockIdx.x * chunk;
    int e = min(E, s + chunk);
    for (int i = s + t; i < e; i += 256)
        atomicAdd(&hist[er[i] >> REGION_SHIFT], 1);
    __syncthreads();
    partial[blockIdx.x * 256 + t] = hist[t];   // single-writer 1KB row
}

// ---- K2a: one block: region totals -> exclusive scan -> region_off ----
__global__ void region_scan_kernel(const int* __restrict__ partial,
                                   int* __restrict__ region_off,
                                   int nreg, int E, int G) {
    __shared__ int s[256];
    int t = threadIdx.x;
    int total = 0;
    if (t < nreg)
        for (int b = 0; b < G; b++) total += partial[b * 256 + t];  // coalesced
    s[t] = (t < nreg) ? total : 0;
    __syncthreads();
    for (int off = 1; off < 256; off <<= 1) {
        int x = (t >= off) ? s[t - off] : 0;
        __syncthreads();
        s[t] += x;
        __syncthreads();
    }
    if (t < nreg) region_off[t] = s[t] - total;
    if (t == 0) region_off[nreg] = E;
}

// ---- K2b: per-region parallel scan over blocks: partial -> scatter bases ----
__global__ void region_base_kernel(int* __restrict__ partial,
                                   const int* __restrict__ region_off, int nreg) {
    __shared__ int s[256];
    int r = blockIdx.x;
    if (r >= nreg) return;
    int t = threadIdx.x;
    int c = partial[t * 256 + r];    // block t's count for region r
    s[t] = c;
    __syncthreads();
    for (int off = 1; off < 256; off <<= 1) {
        int x = (t >= off) ? s[t - off] : 0;
        __syncthreads();
        s[t] += x;
        __syncthreads();
    }
    partial[t * 256 + r] = region_off[r] + s[t] - c;   // exclusive base
}

// ---- K3: coarse scatter, LDS rank only (no global atomics) ----
// stg rec: .x = col | localrow<<17 ; .y = bf16 bits of 0.5*val (15 bits, >=0)
__global__ void coarse_scatter_kernel(const int* __restrict__ er,
                                      const int* __restrict__ ec,
                                      const float* __restrict__ ev, int E,
                                      const int* __restrict__ partial,
                                      int2* __restrict__ stg) {
    __shared__ int cnt2[256], gbase[256];
    int t = threadIdx.x;
    cnt2[t] = 0;
    gbase[t] = partial[blockIdx.x * 256 + t];
    __syncthreads();
    int chunk = (E + gridDim.x - 1) / gridDim.x;   // identical to K1
    int s0 = blockIdx.x * chunk;
    int e0 = min(E, s0 + chunk);
    for (int i = s0 + t; i < e0; i += 256) {
        int r = er[i];
        int b = r >> REGION_SHIFT;
        int rank = atomicAdd(&cnt2[b], 1);
        int2 rec;
        rec.x = ec[i] | ((r & (REGION_SIZE - 1)) << 17);
        rec.y = (int)bf1(0.5f * ev[i]);            // positive: 15 bits
        stg[gbase[b] + rank] = rec;                // block-private run
    }
}

// ---- K4: per-region LDS sort -> row_ptr + packed 4B cv ----
__global__ void region_sort_kernel(const int2* __restrict__ stg,
                                   const int* __restrict__ region_off,
                                   int* __restrict__ row_ptr,
                                   u32* __restrict__ cv, int N, int E) {
    __shared__ int hist[REGION_SIZE];
    __shared__ int wp_local[REGION_SIZE];
    __shared__ int psum[256];
    int cb = blockIdx.x;
    int lo = cb << REGION_SHIFT;
    if (lo >= N) return;
    int hi = min(lo + REGION_SIZE, N);
    int cnt = hi - lo;
    int t = threadIdx.x;
    for (int r = t; r < cnt; r += 256) hist[r] = 0;
    __syncthreads();
    int start = region_off[cb];
    int end   = region_off[cb + 1];
    for (int q = start + t; q < end; q += 256)
        atomicAdd(&hist[stg[q].x >> 17], 1);
    __syncthreads();
    int a0 = (2 * t     < cnt) ? hist[2 * t]     : 0;
    int a1 = (2 * t + 1 < cnt) ? hist[2 * t + 1] : 0;
    psum[t] = a0 + a1;
    __syncthreads();
    for (int off = 1; off < 256; off <<= 1) {
        int x = (t >= off) ? psum[t - off] : 0;
        __syncthreads();
        psum[t] += x;
        __syncthreads();
    }
    int excl = psum[t] - (a0 + a1);
    if (2 * t < cnt) {
        wp_local[2 * t] = start + excl;
        row_ptr[lo + 2 * t] = start + excl;
    }
    if (2 * t + 1 < cnt) {
        wp_local[2 * t + 1] = start + excl + a0;
        row_ptr[lo + 2 * t + 1] = start + excl + a0;
    }
    if (cb == 0 && t == 0) row_ptr[N] = E;
    __syncthreads();
    for (int q = start + t; q < end; q += 256) {
        int2 e = stg[q];
        int lr = e.x >> 17;
        int p = atomicAdd(&wp_local[lr], 1);      // LDS atomic
        cv[p] = ((u32)e.y << 17) | ((u32)e.x & COL_MASK);  // private window
    }
}

// ---------------- CSR SpMM, gather-side, bf16 table / fp32 accum ------------
__device__ inline void fma8(float acc[8], float v, uint4 w) {
    acc[0] = fmaf(v, bflo(w.x), acc[0]); acc[1] = fmaf(v, bfhi(w.x), acc[1]);
    acc[2] = fmaf(v, bflo(w.y), acc[2]); acc[3] = fmaf(v, bfhi(w.y), acc[3]);
    acc[4] = fmaf(v, bflo(w.z), acc[4]); acc[5] = fmaf(v, bfhi(w.z), acc[5]);
    acc[6] = fmaf(v, bflo(w.w), acc[6]); acc[7] = fmaf(v, bfhi(w.w), acc[7]);
}
__device__ inline float cvval(u32 q) { return __uint_as_float((q >> 17) << 16); }

// D features/row; 8 features (16B) per lane; LPR = D/8 lanes per row.
// Simple 4-wide unroll (r10 structure) — compiler schedules the 4 gathers.
template <int D, bool FINAL>
__global__ __launch_bounds__(256) void spmm_bf16_kernel(
        const u16* __restrict__ h,
        const int* __restrict__ row_ptr,
        const u32* __restrict__ cv,
        void* __restrict__ outp,
        const float* __restrict__ bias,  // used iff FINAL
        int N) {
    constexpr int LPR = D / 8;
    int gid = blockIdx.x * 256 + threadIdx.x;
    int row = gid / LPR;
    int sub = gid % LPR;
    if (row >= N) return;
    int start = row_ptr[row];
    int end   = row_ptr[row + 1];
    float acc[8] = {0.f, 0.f, 0.f, 0.f, 0.f, 0.f, 0.f, 0.f};
    int j = start;
    for (; j + 4 <= end; j += 4) {
        u32 q0 = cv[j], q1 = cv[j + 1], q2 = cv[j + 2], q3 = cv[j + 3];
        uint4 w0 = reinterpret_cast<const uint4*>(h + (size_t)(q0 & COL_MASK) * D)[sub];
        uint4 w1 = reinterpret_cast<const uint4*>(h + (size_t)(q1 & COL_MASK) * D)[sub];
        uint4 w2 = reinterpret_cast<const uint4*>(h + (size_t)(q2 & COL_MASK) * D)[sub];
        uint4 w3 = reinterpret_cast<const uint4*>(h + (size_t)(q3 & COL_MASK) * D)[sub];
        fma8(acc, cvval(q0), w0);
        fma8(acc, cvval(q1), w1);
        fma8(acc, cvval(q2), w2);
        fma8(acc, cvval(q3), w3);
    }
    for (; j < end; j++) {
        u32 q = cv[j];
        uint4 w = reinterpret_cast<const uint4*>(h + (size_t)(q & COL_MASK) * D)[sub];
        fma8(acc, cvval(q), w);
    }
    if (FINAL) {
        float* op = (float*)outp + (size_t)row * 64 + sub * 8;
#pragma unroll
        for (int k = 0; k < 8; k++) acc[k] += bias[sub * 8 + k];
        reinterpret_cast<float4*>(op)[0] = make_float4(acc[0], acc[1], acc[2], acc[3]);
        reinterpret_cast<float4*>(op)[1] = make_float4(acc[4], acc[5], acc[6], acc[7]);
    } else {
        u16* ob = (u16*)outp + (size_t)row * D + sub * 8;
        uint4 o;
        o.x = bfpack(acc[0], acc[1]);
        o.y = bfpack(acc[2], acc[3]);
        o.z = bfpack(acc[4], acc[5]);
        o.w = bfpack(acc[6], acc[7]);
        reinterpret_cast<uint4*>(ob)[0] = o;
    }
}

// ------- MFMA dense: t2 = relu(t1@W1 + b1) @ W2, bf16 in/out ----------------
// One wave per 16-row tile. 16x16x32 bf16 MFMA. (verified r10)
__global__ __launch_bounds__(256) void dense_mfma_kernel(
        const u16* __restrict__ h,     // [N,32] bf16
        const float* __restrict__ W1,  // [32,64]
        const float* __restrict__ b1,  // [64]
        const float* __restrict__ W2,  // [64,64]
        u16* __restrict__ outb, int N) {
    __shared__ __align__(16) u16 tiles[4][16][80];  // per-wave tile, pad 80
    int tid = threadIdx.x;
    int lane = tid & 63;
    int wave = tid >> 6;
    int n16 = lane & 15;
    int quad = lane >> 4;
    u16 (*tile)[80] = tiles[wave];

    int tilebase = (blockIdx.x * 4 + wave) * 16;
    if (tilebase >= N) return;          // wave-uniform

    bf16x8 w1f[4];
    bf16x8 w2f[4][2];
#pragma unroll
    for (int t = 0; t < 4; t++) {
#pragma unroll
        for (int j = 0; j < 8; j++) {
            int k = quad * 8 + j;
            w1f[t][j] = (short)bf1(W1[k * 64 + t * 16 + n16]);
            w2f[t][0][j] = (short)bf1(W2[k * 64 + t * 16 + n16]);
            w2f[t][1][j] = (short)bf1(W2[(32 + k) * 64 + t * 16 + n16]);
        }
    }
    float b1v[4];
#pragma unroll
    for (int t = 0; t < 4; t++) b1v[t] = b1[t * 16 + n16];

    int arow = min(tilebase + n16, N - 1);
    bf16x8 a1 = *reinterpret_cast<const bf16x8*>(h + (size_t)arow * 32 + quad * 8);
    f32x4 zero = {0.f, 0.f, 0.f, 0.f};
    f32x4 c[4];
#pragma unroll
    for (int t = 0; t < 4; t++)
        c[t] = __builtin_amdgcn_mfma_f32_16x16x32_bf16(a1, w1f[t], zero, 0, 0, 0);

#pragma unroll
    for (int t = 0; t < 4; t++)
#pragma unroll
        for (int i = 0; i < 4; i++)
            tile[quad * 4 + i][t * 16 + n16] = bf1(fmaxf(c[t][i] + b1v[t], 0.f));

    bf16x8 a2_0 = *reinterpret_cast<const bf16x8*>(&tile[n16][quad * 8]);
    bf16x8 a2_1 = *reinterpret_cast<const bf16x8*>(&tile[n16][32 + quad * 8]);
    f32x4 d[4];
#pragma unroll
    for (int t = 0; t < 4; t++) {
        d[t] = __builtin_amdgcn_mfma_f32_16x16x32_bf16(a2_0, w2f[t][0], zero, 0, 0, 0);
        d[t] = __builtin_amdgcn_mfma_f32_16x16x32_bf16(a2_1, w2f[t][1], d[t], 0, 0, 0);
    }

#pragma unroll
    for (int t = 0; t < 4; t++)
#pragma unroll
        for (int i = 0; i < 4; i++)
            tile[quad * 4 + i][t * 16 + n16] = bf1(d[t][i]);

#pragma unroll
    for (int half = 0; half < 2; half++) {
        int g = half * 512 + lane * 8;
        int r = g >> 6, cc = g & 63;
        int grow = tilebase + r;
        if (grow < N)
            *reinterpret_cast<uint4*>(outb + (size_t)grow * 64 + cc) =
                *reinterpret_cast<const uint4*>(&tile[r][cc]);
    }
}

extern "C" void kernel_launch(void* const* d_in, const int* in_sizes, int n_in,
                              void* d_out, int out_size, void* d_ws, size_t ws_size,
                              hipStream_t stream) {
    const float* x        = (const float*)d_in[0];
    const float* edge_val = (const float*)d_in[1];
    const int*   edge_row = (const int*)d_in[2];
    const int*   edge_col = (const int*)d_in[3];
    const float* W1       = (const float*)d_in[4];
    const float* b1       = (const float*)d_in[5];
    const float* W2       = (const float*)d_in[6];
    const float* b2       = (const float*)d_in[7];
    float* out = (float*)d_out;

    const int N = in_sizes[0] / 32;   // 100000
    const int E = in_sizes[1];        // 1600000
    const int NREG = (N + REGION_SIZE - 1) >> REGION_SHIFT;  // 196

    // --- d_out as raw scratch (fp32 final write overwrites all) ---
    u16* xb  = (u16*)d_out;                    // N*32 bf16
    u16* t0b = xb + (size_t)N * 32;            // N*32 bf16
    u16* t2b = (u16*)d_out + (size_t)N * 64;   // N*64 bf16 (bytes [12.8,25.6MB))

    // --- ws layout ---
    u16*  wsb = (u16*)d_ws;                    // N*64 bf16: t1b then t3b
    int2* stg = (int2*)d_ws;                   // E int2 overlay (build only)
    int*  row_ptr    = (int*)((char*)d_ws + (size_t)N * 64 * 2);  // N+1
    int*  region_off = row_ptr + (N + 1);      // NREG+1
    int*  partial    = region_off + (NREG + 1);// GBUILD*256
    size_t cvOff = (size_t)((char*)(partial + GBUILD * 256) - (char*)d_ws);
    cvOff = (cvOff + 15) & ~(size_t)15;        // 16B align
    u32* cv = (u32*)((char*)d_ws + cvOff);     // E packed 4B edges
    u16* t1b = wsb;
    u16* t3b = wsb;

    int n4 = (N * 32) / 4;

    // ---- CSR build (2-pass radix, zero global atomics, no memset) ----
    region_count_kernel<<<GBUILD, 256, 0, stream>>>(edge_row, E, partial, x, xb, n4);
    region_scan_kernel<<<1, 256, 0, stream>>>(partial, region_off, NREG, E, GBUILD);
    region_base_kernel<<<NREG, 256, 0, stream>>>(partial, region_off, NREG);
    coarse_scatter_kernel<<<GBUILD, 256, 0, stream>>>(edge_row, edge_col, edge_val,
                                                      E, partial, stg);
    region_sort_kernel<<<NREG, 256, 0, stream>>>(stg, region_off, row_ptr, cv, N, E);

    // ---- pipeline ----
    int g32 = (N * 4 + 255) / 256;   // D=32: 4 lanes/row
    int g64 = (N * 8 + 255) / 256;   // D=64: 8 lanes/row

    spmm_bf16_kernel<32, false><<<g32, 256, 0, stream>>>(xb, row_ptr, cv, t0b, nullptr, N);
    spmm_bf16_kernel<32, false><<<g32, 256, 0, stream>>>(t0b, row_ptr, cv, t1b, nullptr, N);
    dense_mfma_kernel<<<(N + 63) / 64, 256, 0, stream>>>(t1b, W1, b1, W2, t2b, N);
    spmm_bf16_kernel<64, false><<<g64, 256, 0, stream>>>(t2b, row_ptr, cv, t3b, nullptr, N);
    spmm_bf16_kernel<64, true><<<g64, 256, 0, stream>>>(t3b, row_ptr, cv, out, b2, N);
}